// Round 1
// 907.016 us; speedup vs baseline: 1.1147x; 1.1147x over previous
//
#include <hip/hip_runtime.h>
#include <hip/hip_bf16.h>
#include <stdint.h>

// Problem constants (exact divisions, no bounds checks needed)
#define M_TOT 16384   // 8*2048 rows of x
#define N_TOT 4096    // output features
#define K_TOT 4096    // input features

typedef unsigned short ushort_t;
typedef __attribute__((ext_vector_type(8))) short short8;   // 8 bf16 = 4 VGPRs (MFMA A/B frag)
typedef __attribute__((ext_vector_type(4))) float f32x4;    // MFMA C/D frag

// RNE fp32 -> bf16 (3 int ops; inputs are finite randoms, no NaN path needed)
__device__ __forceinline__ ushort_t f2bf(float f) {
  union { float f; uint32_t u; } v; v.f = f;
  uint32_t u = v.u;
  return (ushort_t)((u + 0x7FFFu + ((u >> 16) & 1u)) >> 16);
}

// Unpack 6-bit weights: per group of 3 ints -> 4 values (p0&63, (p0>>6)&63, p1&63, p2&63)
__global__ void dequant_w_kernel(const int* __restrict__ q,
                                 const float* __restrict__ scale,
                                 const float* __restrict__ zp,
                                 ushort_t* __restrict__ wbf) {
  int g = blockIdx.x * 256 + threadIdx.x;      // 0 .. 4096*1024-1
  int n   = g >> 10;
  int grp = g & 1023;
  const int* p = q + (size_t)n * 3072 + grp * 3;
  int p0 = p[0], p1 = p[1], p2 = p[2];
  float s = scale[n], z = zp[n];
  ushort4 o;
  o.x = f2bf(((float)(p0 & 63)        - z) * s);
  o.y = f2bf(((float)((p0 >> 6) & 63) - z) * s);
  o.z = f2bf(((float)(p1 & 63)        - z) * s);
  o.w = f2bf(((float)(p2 & 63)        - z) * s);
  *(ushort4*)(wbf + (size_t)n * 4096 + grp * 4) = o;
}

__global__ void convert_x_kernel(const float* __restrict__ x,
                                 ushort_t* __restrict__ xbf) {
  size_t i = (size_t)blockIdx.x * 256 + threadIdx.x;   // float4 chunk index
  float4 v = ((const float4*)x)[i];
  ushort4 o;
  o.x = f2bf(v.x); o.y = f2bf(v.y); o.z = f2bf(v.z); o.w = f2bf(v.w);
  ((ushort4*)xbf)[i] = o;
}

// ================= 256x256 8-phase GEMM (T2+T3+T4+T5) =================
// C[m][n] = sum_k A[m][k]*W[n][k] + bias[n], A/W bf16 row-major stride K.
#define BM 256
#define BN 256
#define BK 64
#define NT (K_TOT / BK)   // 64 K-tiles

__device__ __forceinline__ void gload16(const ushort_t* g, ushort_t* l) {
  // async global->LDS DMA, 16B/lane; LDS dest is wave-uniform base + lane*16
  __builtin_amdgcn_global_load_lds(
      (__attribute__((address_space(1))) void*)g,
      (__attribute__((address_space(3))) void*)l, 16, 0, 0);
}

__device__ __forceinline__ void fencebar() {
  asm volatile("" ::: "memory");     // pin LDS/DMA ops against code motion
  __builtin_amdgcn_s_barrier();      // raw barrier: does NOT drain vmcnt
  asm volatile("" ::: "memory");
}

// 16-MFMA cluster for M-frag pair (I0, I0+1) x 4 N-frags x 2 k-steps
#define MFMA_PAIR(I0)                                                         \
  __builtin_amdgcn_s_setprio(1);                                              \
  _Pragma("unroll")                                                           \
  for (int ii = 0; ii < 2; ++ii) {                                            \
    _Pragma("unroll")                                                         \
    for (int j = 0; j < 4; ++j) {                                             \
      acc[(I0) + ii][j] = __builtin_amdgcn_mfma_f32_16x16x32_bf16(            \
          a[(I0) + ii][0], b[j][0], acc[(I0) + ii][j], 0, 0, 0);              \
      acc[(I0) + ii][j] = __builtin_amdgcn_mfma_f32_16x16x32_bf16(            \
          a[(I0) + ii][1], b[j][1], acc[(I0) + ii][j], 0, 0, 0);              \
    }                                                                         \
  }                                                                           \
  __builtin_amdgcn_s_setprio(0);

__global__ __launch_bounds__(512, 2)
void gemm8p(const ushort_t* __restrict__ A,     // [M][K] bf16
            const ushort_t* __restrict__ W,     // [N][K] bf16
            const float* __restrict__ bias,
            float* __restrict__ out) {
  // [slot][0=A,1=B][256 rows * 64 k] bf16, linear rows (128B pitch). 128 KiB.
  __shared__ ushort_t lds[2][2][BM * BK];

  const int tid  = threadIdx.x;
  const int wid  = tid >> 6;
  const int lane = tid & 63;
  const int wm = wid >> 2;          // 0..1  (M half)
  const int wn = wid & 3;           // 0..3  (N quarter)
  const int lr = lane & 15;
  const int lq = lane >> 4;
  const int bn = blockIdx.x;        // 0..15
  const int bm = blockIdx.y;        // 0..63

  // ---- staging coords (per thread: 2 x 16B chunks per half-tile) ----
  // linear chunk q = tid (+512): phys row rp(+64), phys chunk cp.
  // Swizzle sigma: logical chunk = cp ^ (row&7). DMA writes LINEARLY, so we
  // fetch the inverse-swizzled GLOBAL chunk; ds_read applies sigma on read.
  const int rp = tid >> 3;          // 0..63
  const int cp = tid & 7;
  const int cl = cp ^ (rp & 7);     // (rp+64)&7 == rp&7, so same cl for both loads

  const size_t aRow = (size_t)bm * BM;
  const size_t bRow = (size_t)bn * BN;

  // ---- fragment read offsets (swizzled) ----
  const int rowA = wm * 128 + lr;   // + i*16
  const int rowB = wn * 64  + lr;   // + j*16
  const int cs0 = ((0 + lq) ^ (lr & 7)) * 8;   // k-step 0 chunk, elements
  const int cs1 = ((4 + lq) ^ (lr & 7)) * 8;   // k-step 1 chunk

  f32x4 zero = {0.f, 0.f, 0.f, 0.f};
  f32x4 acc[8][4];
#pragma unroll
  for (int i = 0; i < 8; ++i)
#pragma unroll
    for (int j = 0; j < 4; ++j) acc[i][j] = zero;

  // stage one half-tile (h=0: rows 0-127, h=1: rows 128-255) of tile tau
  auto stage = [&](int tau, int ab, int h) {
    const ushort_t* gp =
        (ab ? W + (bRow + (size_t)(h * 128 + rp)) * K_TOT
            : A + (aRow + (size_t)(h * 128 + rp)) * K_TOT)
        + tau * BK + cl * 8;
    ushort_t* lp = &lds[tau & 1][ab][(h * 128 + rp) * BK + cp * 8];
    gload16(gp, lp);
    gload16(gp + (size_t)64 * K_TOT, lp + 64 * BK);
  };

  // ---- prologue: tile0 fully + tile1 halves #1..#3 (7 halves, 14 loads) ----
  stage(0, 1, 0); stage(0, 1, 1); stage(0, 0, 0); stage(0, 0, 1);
  stage(1, 1, 0); stage(1, 1, 1); stage(1, 0, 0);
  asm volatile("s_waitcnt vmcnt(6)" ::: "memory");  // tile0 landed (newest 3 halves may fly)
  __builtin_amdgcn_s_barrier();
  asm volatile("" ::: "memory");

  // Stage rotation (1 half/phase): tile t+1 #4=A-h1 at (t,p1);
  // tile t+2 #1=B-h0 at (t,p2), #2=B-h1 at (t,p3), #3=A-h0 at (t,p4).
  // Read schedule: all B + A0-1 at p1, A2-5 at p2, A6-7 at p3 -> every
  // overwrite is behind the phase-end barrier of its last reader.
  for (int t = 0; t < NT; ++t) {
    const ushort_t* As = &lds[t & 1][0][0];
    const ushort_t* Bs = &lds[t & 1][1][0];
    short8 a[8][2], b[4][2];

    // ---------------- phase 1: read B0-3 + A0-1 (12 ds_read_b128) ----------
#pragma unroll
    for (int j = 0; j < 4; ++j) {
      b[j][0] = *(const short8*)&Bs[(rowB + j * 16) * BK + cs0];
      b[j][1] = *(const short8*)&Bs[(rowB + j * 16) * BK + cs1];
    }
#pragma unroll
    for (int i = 0; i < 2; ++i) {
      a[i][0] = *(const short8*)&As[(rowA + i * 16) * BK + cs0];
      a[i][1] = *(const short8*)&As[(rowA + i * 16) * BK + cs1];
    }
    if (t + 1 < NT) stage(t + 1, 0, 1);          // tile t+1 A-h1 (#4)
    fencebar();
    asm volatile("s_waitcnt lgkmcnt(0)" ::: "memory");
    __builtin_amdgcn_sched_barrier(0);
    MFMA_PAIR(0)
    fencebar();

    // ---------------- phase 2: read A2-5 (8 reads) -------------------------
#pragma unroll
    for (int i = 2; i < 6; ++i) {
      a[i][0] = *(const short8*)&As[(rowA + i * 16) * BK + cs0];
      a[i][1] = *(const short8*)&As[(rowA + i * 16) * BK + cs1];
    }
    if (t + 2 < NT) stage(t + 2, 1, 0);          // tile t+2 B-h0 (#1): B reads done @p1
    fencebar();
    asm volatile("s_waitcnt lgkmcnt(0)" ::: "memory");
    __builtin_amdgcn_sched_barrier(0);
    MFMA_PAIR(2)
    fencebar();

    // ---------------- phase 3: read A6-7 (4 reads) -------------------------
#pragma unroll
    for (int i = 6; i < 8; ++i) {
      a[i][0] = *(const short8*)&As[(rowA + i * 16) * BK + cs0];
      a[i][1] = *(const short8*)&As[(rowA + i * 16) * BK + cs1];
    }
    if (t + 2 < NT) stage(t + 2, 1, 1);          // tile t+2 B-h1 (#2)
    fencebar();
    asm volatile("s_waitcnt lgkmcnt(0)" ::: "memory");
    __builtin_amdgcn_sched_barrier(0);
    MFMA_PAIR(4)
    fencebar();

    // ---------------- phase 4: no reads; counted vmcnt ---------------------
    if (t + 2 < NT) stage(t + 2, 0, 0);          // tile t+2 A-h0 (#3): A reads done @p3
    if (t < NT - 2) {
      // newest 3 halves (t+2 #1-#3) may stay in flight; tile t+1 is landed
      asm volatile("s_waitcnt vmcnt(6)" ::: "memory");
    } else {
      asm volatile("s_waitcnt vmcnt(0)" ::: "memory");   // drain tail
    }
    fencebar();
    MFMA_PAIR(6)
    fencebar();
  }

  // ---- epilogue: C/D layout col=lane&15, row=(lane>>4)*4+reg ----
  float bv[4];
#pragma unroll
  for (int j = 0; j < 4; ++j)
    bv[j] = bias[bn * BN + wn * 64 + j * 16 + lr];

#pragma unroll
  for (int i = 0; i < 8; ++i) {
    int m0 = bm * BM + wm * 128 + i * 16 + lq * 4;
#pragma unroll
    for (int j = 0; j < 4; ++j) {
      int n0 = bn * BN + wn * 64 + j * 16 + lr;
      float* po = out + (size_t)m0 * N_TOT + n0;
#pragma unroll
      for (int r = 0; r < 4; ++r)
        po[(size_t)r * N_TOT] = acc[i][j][r] + bv[j];
    }
  }
}

// ============== fallback: 128x128 kernel, fp32 A on the fly ==============
// (only used when the workspace cannot hold the bf16 copy of x)
#define FB_BM 128
#define FB_BN 128
#define FB_BK 64
#define FB_LDK 72

__global__ __launch_bounds__(256, 2)
void gemm_fb(const float* __restrict__ Aptr,
             const ushort_t* __restrict__ W,
             const float* __restrict__ bias,
             float* __restrict__ out) {
  __shared__ ushort_t Ab[FB_BM * FB_LDK];
  __shared__ ushort_t Bb[FB_BN * FB_LDK];

  const int tid = threadIdx.x;
  const int bn = blockIdx.x;
  const int bm = blockIdx.y;
  const int w  = tid >> 6;
  const int l  = tid & 63;
  const int wr = (w >> 1) * 64;
  const int wc = (w & 1) * 64;
  const int lr = l & 15;
  const int lq = l >> 4;

  f32x4 zero = {0.f, 0.f, 0.f, 0.f};
  f32x4 acc[4][4];
#pragma unroll
  for (int i = 0; i < 4; ++i)
#pragma unroll
    for (int j = 0; j < 4; ++j) acc[i][j] = zero;

  const size_t aRowBase = (size_t)bm * FB_BM;
  const size_t bRowBase = (size_t)bn * FB_BN;

  for (int k0 = 0; k0 < K_TOT; k0 += FB_BK) {
    const float* Ag = Aptr + aRowBase * K_TOT + k0;
#pragma unroll
    for (int i = 0; i < 8; ++i) {
      int id = tid + i * 256;
      int r = id >> 4;
      int c = (id & 15) << 2;
      float4 v = *(const float4*)(Ag + (size_t)r * K_TOT + c);
      ushort4 o;
      o.x = f2bf(v.x); o.y = f2bf(v.y); o.z = f2bf(v.z); o.w = f2bf(v.w);
      *(ushort4*)(&Ab[r * FB_LDK + c]) = o;
    }
    {
      const ushort_t* Bg = W + bRowBase * K_TOT + k0;
#pragma unroll
      for (int i = 0; i < 4; ++i) {
        int id = tid + i * 256;
        int r = id >> 3;
        int c = (id & 7) << 3;
        float4 v = *(const float4*)(Bg + (size_t)r * K_TOT + c);
        *(float4*)(&Bb[r * FB_LDK + c]) = v;
      }
    }
    __syncthreads();

#pragma unroll
    for (int kk = 0; kk < FB_BK; kk += 32) {
      short8 af[4], bfr[4];
#pragma unroll
      for (int i = 0; i < 4; ++i)
        af[i] = *(const short8*)(&Ab[(wr + i * 16 + lr) * FB_LDK + kk + lq * 8]);
#pragma unroll
      for (int j = 0; j < 4; ++j)
        bfr[j] = *(const short8*)(&Bb[(wc + j * 16 + lr) * FB_LDK + kk + lq * 8]);
#pragma unroll
      for (int i = 0; i < 4; ++i)
#pragma unroll
        for (int j = 0; j < 4; ++j)
          acc[i][j] = __builtin_amdgcn_mfma_f32_16x16x32_bf16(af[i], bfr[j], acc[i][j], 0, 0, 0);
    }
    __syncthreads();
  }

  float bv[4];
#pragma unroll
  for (int j = 0; j < 4; ++j)
    bv[j] = bias[bn * FB_BN + wc + j * 16 + lr];

#pragma unroll
  for (int i = 0; i < 4; ++i) {
    int m0 = bm * FB_BM + wr + i * 16 + lq * 4;
#pragma unroll
    for (int j = 0; j < 4; ++j) {
      int n0 = bn * FB_BN + wc + j * 16 + lr;
      float* po = out + (size_t)m0 * N_TOT + n0;
#pragma unroll
      for (int r = 0; r < 4; ++r)
        po[(size_t)r * N_TOT] = acc[i][j][r] + bv[j];
    }
  }
}

extern "C" void kernel_launch(void* const* d_in, const int* in_sizes, int n_in,
                              void* d_out, int out_size, void* d_ws, size_t ws_size,
                              hipStream_t stream) {
  const float* x     = (const float*)d_in[0];   // (8,2048,4096) fp32
  const int*   qw    = (const int*)d_in[1];     // (4096,3072) int32
  const float* scale = (const float*)d_in[2];   // (4096,1)
  const float* zp    = (const float*)d_in[3];   // (4096,1)
  const float* bias  = (const float*)d_in[4];   // (4096,)
  float* out = (float*)d_out;

  const size_t WBF = (size_t)N_TOT * K_TOT * sizeof(ushort_t);  // 33.5 MB
  const size_t XBF = (size_t)M_TOT * K_TOT * sizeof(ushort_t);  // 134 MB
  ushort_t* wbf = (ushort_t*)d_ws;

  // d_ws is re-poisoned before every call -> recompute every call (required anyway).
  dequant_w_kernel<<<(N_TOT * 1024) / 256, 256, 0, stream>>>(qw, scale, zp, wbf);

  if (ws_size >= WBF + XBF) {
    ushort_t* xbf = (ushort_t*)((char*)d_ws + WBF);
    convert_x_kernel<<<(size_t)M_TOT * K_TOT / 4 / 256, 256, 0, stream>>>(x, xbf);
    dim3 grid(N_TOT / BN, M_TOT / BM);   // 16 x 64 = 1024 blocks
    gemm8p<<<grid, 512, 0, stream>>>(xbf, wbf, bias, out);
  } else {
    dim3 grid(N_TOT / FB_BN, M_TOT / FB_BM);
    gemm_fb<<<grid, 256, 0, stream>>>(x, wbf, bias, out);
  }
}

// Round 2
// 877.655 us; speedup vs baseline: 1.1520x; 1.0335x over previous
//
#include <hip/hip_runtime.h>
#include <hip/hip_bf16.h>
#include <stdint.h>

// Problem constants (exact divisions, no bounds checks needed)
#define M_TOT 16384   // 8*2048 rows of x
#define N_TOT 4096    // output features
#define K_TOT 4096    // input features

typedef unsigned short ushort_t;
typedef __attribute__((ext_vector_type(8))) short short8;   // 8 bf16 = 4 VGPRs (MFMA A/B frag)
typedef __attribute__((ext_vector_type(4))) float f32x4;    // MFMA C/D frag

// RNE fp32 -> bf16 (3 int ops; inputs are finite randoms, no NaN path needed)
__device__ __forceinline__ ushort_t f2bf(float f) {
  union { float f; uint32_t u; } v; v.f = f;
  uint32_t u = v.u;
  return (ushort_t)((u + 0x7FFFu + ((u >> 16) & 1u)) >> 16);
}

// Unpack 6-bit weights: per group of 3 ints -> 4 values (p0&63, (p0>>6)&63, p1&63, p2&63)
__global__ void dequant_w_kernel(const int* __restrict__ q,
                                 const float* __restrict__ scale,
                                 const float* __restrict__ zp,
                                 ushort_t* __restrict__ wbf) {
  int g = blockIdx.x * 256 + threadIdx.x;      // 0 .. 4096*1024-1
  int n   = g >> 10;
  int grp = g & 1023;
  const int* p = q + (size_t)n * 3072 + grp * 3;
  int p0 = p[0], p1 = p[1], p2 = p[2];
  float s = scale[n], z = zp[n];
  ushort4 o;
  o.x = f2bf(((float)(p0 & 63)        - z) * s);
  o.y = f2bf(((float)((p0 >> 6) & 63) - z) * s);
  o.z = f2bf(((float)(p1 & 63)        - z) * s);
  o.w = f2bf(((float)(p2 & 63)        - z) * s);
  *(ushort4*)(wbf + (size_t)n * 4096 + grp * 4) = o;
}

__global__ void convert_x_kernel(const float* __restrict__ x,
                                 ushort_t* __restrict__ xbf) {
  size_t i = (size_t)blockIdx.x * 256 + threadIdx.x;   // float4 chunk index
  float4 v = ((const float4*)x)[i];
  ushort4 o;
  o.x = f2bf(v.x); o.y = f2bf(v.y); o.z = f2bf(v.z); o.w = f2bf(v.w);
  ((ushort4*)xbf)[i] = o;
}

// ================= 256x256 read-ahead 4-phase GEMM =================
// C[m][n] = sum_k A[m][k]*W[n][k] + bias[n], A/W bf16 row-major stride K.
// Per K-tile: 4 C-quadrant phases; each phase's ds_reads were issued in the
// PREVIOUS phase (between entry lgkmcnt(0) and MFMA) so LDS latency hides
// under the 16-MFMA cluster. Quadrant order a03b01, a03b23, a47b01, a47b23
// guarantees single-buffered frags (next-tile read always after last use).
#define BM 256
#define BN 256
#define BK 64
#define NT (K_TOT / BK)   // 64 K-tiles

__device__ __forceinline__ void gload16(const ushort_t* g, ushort_t* l) {
  // async global->LDS DMA, 16B/lane; LDS dest is wave-uniform base + lane*16
  __builtin_amdgcn_global_load_lds(
      (__attribute__((address_space(1))) void*)g,
      (__attribute__((address_space(3))) void*)l, 16, 0, 0);
}

__device__ __forceinline__ void fencebar() {
  asm volatile("" ::: "memory");     // pin LDS/DMA ops against code motion
  __builtin_amdgcn_s_barrier();      // raw barrier: does NOT drain vmcnt
  asm volatile("" ::: "memory");
}

// 16-MFMA cluster: a-frags I0..I0+3 x b-frags J0..J0+1 x 2 k-steps
#define QUAD(I0, J0)                                                          \
  __builtin_amdgcn_s_setprio(1);                                              \
  _Pragma("unroll")                                                           \
  for (int ii = 0; ii < 4; ++ii) {                                            \
    _Pragma("unroll")                                                         \
    for (int jj = 0; jj < 2; ++jj) {                                          \
      acc[(I0) + ii][(J0) + jj] = __builtin_amdgcn_mfma_f32_16x16x32_bf16(    \
          a[(I0) + ii][0], b[(J0) + jj][0], acc[(I0) + ii][(J0) + jj], 0, 0, 0); \
      acc[(I0) + ii][(J0) + jj] = __builtin_amdgcn_mfma_f32_16x16x32_bf16(    \
          a[(I0) + ii][1], b[(J0) + jj][1], acc[(I0) + ii][(J0) + jj], 0, 0, 0); \
    }                                                                         \
  }                                                                           \
  __builtin_amdgcn_s_setprio(0);

__global__ __launch_bounds__(512, 2)
void gemm8p(const ushort_t* __restrict__ A,     // [M][K] bf16
            const ushort_t* __restrict__ W,     // [N][K] bf16
            const float* __restrict__ bias,
            float* __restrict__ out) {
  // [slot][0=A,1=B][256 rows * 64 k] bf16, linear rows (128B pitch). 128 KiB.
  __shared__ ushort_t lds[2][2][BM * BK];

  const int tid  = threadIdx.x;
  const int wid  = tid >> 6;
  const int lane = tid & 63;
  const int wm = wid >> 2;          // 0..1  (M half)
  const int wn = wid & 3;           // 0..3  (N quarter)
  const int lr = lane & 15;
  const int lq = lane >> 4;
  const int bn = blockIdx.x;        // 0..15
  const int bm = blockIdx.y;        // 0..63

  // ---- staging coords (per thread: 2 x 16B chunks per half-tile) ----
  // DMA writes LINEARLY; fetch the inverse-swizzled GLOBAL chunk so that the
  // swizzled ds_read (chunk ^ (row&7)) sees the right data (both-sides rule).
  const int rp = tid >> 3;          // 0..63
  const int cp = tid & 7;
  const int cl = cp ^ (rp & 7);     // (rp+64)&7 == rp&7, so same cl for both loads

  const size_t aRow = (size_t)bm * BM;
  const size_t bRow = (size_t)bn * BN;

  // ---- fragment read offsets (swizzled) ----
  const int rowA = wm * 128 + lr;   // + i*16
  const int rowB = wn * 64  + lr;   // + j*16
  const int cs0 = ((0 + lq) ^ (lr & 7)) * 8;   // k-step 0 chunk, elements
  const int cs1 = ((4 + lq) ^ (lr & 7)) * 8;   // k-step 1 chunk

  f32x4 zero = {0.f, 0.f, 0.f, 0.f};
  f32x4 acc[8][4];
#pragma unroll
  for (int i = 0; i < 8; ++i)
#pragma unroll
    for (int j = 0; j < 4; ++j) acc[i][j] = zero;

  short8 a[8][2], b[4][2];

  // stage one half-tile (h=0: rows 0-127, h=1: rows 128-255) of tile tau
  auto stage = [&](int tau, int ab, int h) {
    const ushort_t* gp =
        (ab ? W + (bRow + (size_t)(h * 128 + rp)) * K_TOT
            : A + (aRow + (size_t)(h * 128 + rp)) * K_TOT)
        + tau * BK + cl * 8;
    ushort_t* lp = &lds[tau & 1][ab][(h * 128 + rp) * BK + cp * 8];
    gload16(gp, lp);
    gload16(gp + (size_t)64 * K_TOT, lp + 64 * BK);
  };
  // read 2 b-frags (j0, j0+1), both k-steps: 4 ds_read_b128
  auto readB = [&](const ushort_t* Bs_, int j0) {
#pragma unroll
    for (int j = 0; j < 2; ++j) {
      b[j0 + j][0] = *(const short8*)&Bs_[(rowB + (j0 + j) * 16) * BK + cs0];
      b[j0 + j][1] = *(const short8*)&Bs_[(rowB + (j0 + j) * 16) * BK + cs1];
    }
  };
  // read 4 a-frags (i0..i0+3), both k-steps: 8 ds_read_b128
  auto readA = [&](const ushort_t* As_, int i0) {
#pragma unroll
    for (int i = 0; i < 4; ++i) {
      a[i0 + i][0] = *(const short8*)&As_[(rowA + (i0 + i) * 16) * BK + cs0];
      a[i0 + i][1] = *(const short8*)&As_[(rowA + (i0 + i) * 16) * BK + cs1];
    }
  };

  // ---- prologue: tile0 fully + tile1 Bh0,Bh1,Ah0 (7 halves, 14 loads) ----
  // (tile1 Ah1 is staged at P1 of tile0, matching the steady-state rotation)
  stage(0, 1, 0); stage(0, 1, 1); stage(0, 0, 0); stage(0, 0, 1);
  stage(1, 1, 0); stage(1, 1, 1); stage(1, 0, 0);
  asm volatile("s_waitcnt vmcnt(6)" ::: "memory");  // tile0 landed (per-wave)
  fencebar();                                       // -> landed for ALL waves
  readA(&lds[0][0][0], 0);   // a03(0)
  readB(&lds[0][1][0], 0);   // b01(0)   (12 reads; drained at P1 entry)

  // Stage rotation per tile u: P1: A-h1(u+1); P3: B-h0(u+2); P4: B-h1(u+2)+A-h0(u+2).
  // Hazard proof sketch (all cross-wave via the remaining barriers):
  //  * B(u) reads issued @P4(u-1)+P1(u), drained @P2(u) entry, barrier end-P2
  //    -> B(u+2) staging from P3(u) is safe.
  //  * A(u) reads issued @P4(u-1)+P2(u), drained @P3(u) entry, barrier end-P3
  //    -> A(u+2) staging from P4(u) safe; A(u+1)-h1 @P1(u) overwrites A(u-1)-h1,
  //      safe since end-P3(u-1) < P1(u).
  //  * P4 reads tile u+1: per-wave vmcnt(6) drains through A-h1(u+1)@P1(u);
  //    the mid-P4 barrier makes that true for every wave before any wave reads.
  for (int u = 0; u < NT; ++u) {
    const int sl = u & 1;
    const ushort_t* As  = &lds[sl][0][0];
    const ushort_t* Bs  = &lds[sl][1][0];
    const ushort_t* As1 = &lds[sl ^ 1][0][0];
    const ushort_t* Bs1 = &lds[sl ^ 1][1][0];

    // ---- P1: MFMA a03xb01 | issue b23(u), stage A-h1(u+1) ----
    asm volatile("s_waitcnt lgkmcnt(0)" ::: "memory");   // a03,b01(u) landed (free)
    __builtin_amdgcn_sched_barrier(0);
    readB(Bs, 2);                                        // b23(u), used @P2/P4
    if (u + 1 < NT) stage(u + 1, 0, 1);
    __builtin_amdgcn_sched_barrier(0);
    QUAD(0, 0)
    fencebar();

    // ---- P2: MFMA a03xb23 | issue a47(u) ----
    asm volatile("s_waitcnt lgkmcnt(0)" ::: "memory");   // b23(u) landed (free)
    __builtin_amdgcn_sched_barrier(0);
    readA(As, 4);                                        // a47(u), used @P3/P4
    __builtin_amdgcn_sched_barrier(0);
    QUAD(0, 2)
    fencebar();

    // ---- P3: MFMA a47xb01 | stage B-h0(u+2) ----
    asm volatile("s_waitcnt lgkmcnt(0)" ::: "memory");   // a47(u) landed (free)
    __builtin_amdgcn_sched_barrier(0);
    if (u + 2 < NT) stage(u + 2, 1, 0);
    __builtin_amdgcn_sched_barrier(0);
    QUAD(4, 0)
    fencebar();

    // ---- P4: MFMA a47xb23 | stage B-h1,A-h0(u+2); vmcnt; barrier; read tile u+1 ----
    if (u + 2 < NT) { stage(u + 2, 1, 1); stage(u + 2, 0, 0); }
    if (u + 1 < NT) {
      if (u + 2 < NT) {
        // in flight: Bh0(u+2)@P3 [2] + Bh1,Ah0(u+2)@P4 [4]; drain older = tile u+1
        asm volatile("s_waitcnt vmcnt(6)" ::: "memory");
      } else {
        asm volatile("s_waitcnt vmcnt(0)" ::: "memory");  // tail drain
      }
    }
    fencebar();                    // ALL waves' tile u+1 DMA landed past here
    if (u + 1 < NT) {
      readA(As1, 0);               // a03(u+1): a03(u) last used @P2, no WAR
      readB(Bs1, 0);               // b01(u+1): b01(u) last used @P3, no WAR
    }
    __builtin_amdgcn_sched_barrier(0);
    QUAD(4, 2)
    fencebar();
  }

  // ---- epilogue: C/D layout col=lane&15, row=(lane>>4)*4+reg ----
  float bv[4];
#pragma unroll
  for (int j = 0; j < 4; ++j)
    bv[j] = bias[bn * BN + wn * 64 + j * 16 + lr];

#pragma unroll
  for (int i = 0; i < 8; ++i) {
    int m0 = bm * BM + wm * 128 + i * 16 + lq * 4;
#pragma unroll
    for (int j = 0; j < 4; ++j) {
      int n0 = bn * BN + wn * 64 + j * 16 + lr;
      float* po = out + (size_t)m0 * N_TOT + n0;
#pragma unroll
      for (int r = 0; r < 4; ++r)
        po[(size_t)r * N_TOT] = acc[i][j][r] + bv[j];
    }
  }
}

// ============== fallback: 128x128 kernel, fp32 A on the fly ==============
// (only used when the workspace cannot hold the bf16 copy of x)
#define FB_BM 128
#define FB_BN 128
#define FB_BK 64
#define FB_LDK 72

__global__ __launch_bounds__(256, 2)
void gemm_fb(const float* __restrict__ Aptr,
             const ushort_t* __restrict__ W,
             const float* __restrict__ bias,
             float* __restrict__ out) {
  __shared__ ushort_t Ab[FB_BM * FB_LDK];
  __shared__ ushort_t Bb[FB_BN * FB_LDK];

  const int tid = threadIdx.x;
  const int bn = blockIdx.x;
  const int bm = blockIdx.y;
  const int w  = tid >> 6;
  const int l  = tid & 63;
  const int wr = (w >> 1) * 64;
  const int wc = (w & 1) * 64;
  const int lr = l & 15;
  const int lq = l >> 4;

  f32x4 zero = {0.f, 0.f, 0.f, 0.f};
  f32x4 acc[4][4];
#pragma unroll
  for (int i = 0; i < 4; ++i)
#pragma unroll
    for (int j = 0; j < 4; ++j) acc[i][j] = zero;

  const size_t aRowBase = (size_t)bm * FB_BM;
  const size_t bRowBase = (size_t)bn * FB_BN;

  for (int k0 = 0; k0 < K_TOT; k0 += FB_BK) {
    const float* Ag = Aptr + aRowBase * K_TOT + k0;
#pragma unroll
    for (int i = 0; i < 8; ++i) {
      int id = tid + i * 256;
      int r = id >> 4;
      int c = (id & 15) << 2;
      float4 v = *(const float4*)(Ag + (size_t)r * K_TOT + c);
      ushort4 o;
      o.x = f2bf(v.x); o.y = f2bf(v.y); o.z = f2bf(v.z); o.w = f2bf(v.w);
      *(ushort4*)(&Ab[r * FB_LDK + c]) = o;
    }
    {
      const ushort_t* Bg = W + bRowBase * K_TOT + k0;
#pragma unroll
      for (int i = 0; i < 4; ++i) {
        int id = tid + i * 256;
        int r = id >> 3;
        int c = (id & 7) << 3;
        float4 v = *(const float4*)(Bg + (size_t)r * K_TOT + c);
        *(float4*)(&Bb[r * FB_LDK + c]) = v;
      }
    }
    __syncthreads();

#pragma unroll
    for (int kk = 0; kk < FB_BK; kk += 32) {
      short8 af[4], bfr[4];
#pragma unroll
      for (int i = 0; i < 4; ++i)
        af[i] = *(const short8*)(&Ab[(wr + i * 16 + lr) * FB_LDK + kk + lq * 8]);
#pragma unroll
      for (int j = 0; j < 4; ++j)
        bfr[j] = *(const short8*)(&Bb[(wc + j * 16 + lr) * FB_LDK + kk + lq * 8]);
#pragma unroll
      for (int i = 0; i < 4; ++i)
#pragma unroll
        for (int j = 0; j < 4; ++j)
          acc[i][j] = __builtin_amdgcn_mfma_f32_16x16x32_bf16(af[i], bfr[j], acc[i][j], 0, 0, 0);
    }
    __syncthreads();
  }

  float bv[4];
#pragma unroll
  for (int j = 0; j < 4; ++j)
    bv[j] = bias[bn * FB_BN + wc + j * 16 + lr];

#pragma unroll
  for (int i = 0; i < 4; ++i) {
    int m0 = bm * FB_BM + wr + i * 16 + lq * 4;
#pragma unroll
    for (int j = 0; j < 4; ++j) {
      int n0 = bn * FB_BN + wc + j * 16 + lr;
      float* po = out + (size_t)m0 * N_TOT + n0;
#pragma unroll
      for (int r = 0; r < 4; ++r)
        po[(size_t)r * N_TOT] = acc[i][j][r] + bv[j];
    }
  }
}

extern "C" void kernel_launch(void* const* d_in, const int* in_sizes, int n_in,
                              void* d_out, int out_size, void* d_ws, size_t ws_size,
                              hipStream_t stream) {
  const float* x     = (const float*)d_in[0];   // (8,2048,4096) fp32
  const int*   qw    = (const int*)d_in[1];     // (4096,3072) int32
  const float* scale = (const float*)d_in[2];   // (4096,1)
  const float* zp    = (const float*)d_in[3];   // (4096,1)
  const float* bias  = (const float*)d_in[4];   // (4096,)
  float* out = (float*)d_out;

  const size_t WBF = (size_t)N_TOT * K_TOT * sizeof(ushort_t);  // 33.5 MB
  const size_t XBF = (size_t)M_TOT * K_TOT * sizeof(ushort_t);  // 134 MB
  ushort_t* wbf = (ushort_t*)d_ws;

  // d_ws is re-poisoned before every call -> recompute every call (required anyway).
  dequant_w_kernel<<<(N_TOT * 1024) / 256, 256, 0, stream>>>(qw, scale, zp, wbf);

  if (ws_size >= WBF + XBF) {
    ushort_t* xbf = (ushort_t*)((char*)d_ws + WBF);
    convert_x_kernel<<<(size_t)M_TOT * K_TOT / 4 / 256, 256, 0, stream>>>(x, xbf);
    dim3 grid(N_TOT / BN, M_TOT / BM);   // 16 x 64 = 1024 blocks
    gemm8p<<<grid, 512, 0, stream>>>(xbf, wbf, bias, out);
  } else {
    dim3 grid(N_TOT / FB_BN, M_TOT / FB_BM);
    gemm_fb<<<grid, 256, 0, stream>>>(x, wbf, bias, out);
  }
}